// Round 1
// 284.071 us; speedup vs baseline: 1.0136x; 1.0136x over previous
//
#include <hip/hip_runtime.h>
#include <cstdint>
#include <cstddef>

// Problem constants
#define Bc  4
#define Sc  2048
#define Dc  1024
#define Hc  16
#define DDc 64
#define Nc  256   // pooled length

typedef unsigned short u16;
typedef unsigned int   u32;
typedef __bf16 bf16_t;
typedef bf16_t bf16x8 __attribute__((ext_vector_type(8)));
typedef float  f32x4  __attribute__((ext_vector_type(4)));

__device__ __forceinline__ u16 f2bf(float x) {
    u32 u = __float_as_uint(x);
    return (u16)((u + 0x7FFFu + ((u >> 16) & 1u)) >> 16);   // RNE
}
__device__ __forceinline__ u32 pack2(float a, float b) {
    return (u32)f2bf(a) | ((u32)f2bf(b) << 16);
}
__device__ __forceinline__ uint2 pack4(float4 x) {
    return make_uint2(pack2(x.x, x.y), pack2(x.z, x.w));
}
__device__ __forceinline__ float bf2f(u16 x) {
    return __uint_as_float((u32)x << 16);
}
__device__ __forceinline__ float4 f4add(float4 a, float4 b) {
    return make_float4(a.x + b.x, a.y + b.y, a.z + b.z, a.w + b.w);
}

// async global->LDS, 16B per lane
__device__ __forceinline__ void gload_lds16(const void* gp, void* lp) {
    __builtin_amdgcn_global_load_lds(
        reinterpret_cast<const __attribute__((address_space(1))) void*>(
            reinterpret_cast<uintptr_t>(gp)),
        reinterpret_cast<__attribute__((address_space(3))) void*>(
            reinterpret_cast<uintptr_t>(lp)),
        16, 0, 0);
}

// ------------- cast + transpose 4 weights: W[K][N] fp32 -> Wt[N][K] bf16 -------------
__global__ __launch_bounds__(256) void cast_wt4_kernel(
    const float* __restrict__ Wq, const float* __restrict__ Wk,
    const float* __restrict__ Wv, const float* __restrict__ Wc,
    u16* __restrict__ Wt4)
{
    __shared__ float T[64][65];
    const int z = blockIdx.z;
    const float* W = (z == 0) ? Wq : (z == 1) ? Wk : (z == 2) ? Wv : Wc;
    u16* Wt = Wt4 + ((size_t)z << 20);
    const int k0 = blockIdx.y * 64, n0 = blockIdx.x * 64;
    const int c = threadIdx.x & 63, r4 = threadIdx.x >> 6;
    #pragma unroll
    for (int i = 0; i < 16; ++i) {
        int r = i * 4 + r4;
        T[r][c] = W[(size_t)(k0 + r) * 1024 + n0 + c];
    }
    __syncthreads();
    #pragma unroll
    for (int i = 0; i < 16; ++i) {
        int r = i * 4 + r4;
        Wt[(size_t)(n0 + r) * 1024 + k0 + c] = f2bf(T[c][r]);
    }
}

// ------------- staging: 3 bf16 sections per input into Rall -------------
// Each thread owns the DISJOINT 8-row window [8t-1, 8t+6] (one float4 column slice):
//   sec1[t] = x[8t-1] (first row; 0 for t==0)
//   sec2[t] = x[8t]   (second row)
//   sec0[t+1] = sum of the 8 rows  (sec0[t] = sum x[8t-9..8t-2])
//   sec0[0] = 0 (written by thread t==0)
// All 8 loads are unconditional for t>=1 (t is block-uniform), so they batch
// into registers and issue back-to-back (vs the old per-load >=0 guards that
// serialized load->vmcnt(0)->add chains at 16 VGPRs).
__global__ __launch_bounds__(256) void stage_kernel(
    const float* __restrict__ q, const float* __restrict__ k,
    const float* __restrict__ v, u16* __restrict__ R)
{
    int gid = blockIdx.x * 256 + threadIdx.x;       // over 3 * 2^18 float4-groups
    int c4 = gid & 255, t = (gid >> 8) & 255, b = (gid >> 16) & 3, inp = gid >> 18;
    const float* src = (inp == 0) ? q : (inp == 1) ? k : v;
    const float4* Xb = (const float4*)(src + (size_t)b * Sc * Dc) + c4;
    const float4* Xr = Xb + ((ptrdiff_t)(t << 3) - 1) * 256;   // row 8t-1

    float4 r[8];
    if (t > 0) {
        #pragma unroll
        for (int i = 0; i < 8; ++i) r[i] = Xr[(ptrdiff_t)i * 256];
    } else {
        r[0] = make_float4(0.f, 0.f, 0.f, 0.f);
        #pragma unroll
        for (int i = 1; i < 8; ++i) r[i] = Xr[(ptrdiff_t)i * 256];
    }

    float4 s8 = f4add(f4add(f4add(r[0], r[1]), f4add(r[2], r[3])),
                      f4add(f4add(r[4], r[5]), f4add(r[6], r[7])));

    size_t s0 = ((size_t)(inp * 3) << 20) + (((u32)(b * 256 + t)) << 10) + c4 * 4;
    *(uint2*)(R + s0 + (1u << 20)) = pack4(r[0]);        // sec1[t] = x[8t-1]
    *(uint2*)(R + s0 + (2u << 20)) = pack4(r[1]);        // sec2[t] = x[8t]
    if (t < 255) *(uint2*)(R + s0 + 1024) = pack4(s8);   // sec0[t+1]
    if (t == 0)  *(uint2*)(R + s0) = make_uint2(0u, 0u); // sec0[0] = 0
}

// ------------- section GEMM, in-place: Y_z = A_z @ Wt_inp^T (bf16 out over A_z) -------------
__global__ __launch_bounds__(256) void gemm_sec(
    u16* __restrict__ Rall, const u16* __restrict__ Wt4)
{
    __shared__ __align__(16) u16 As[128 * 32];
    __shared__ __align__(16) u16 Bs[128 * 32];

    const int tid  = threadIdx.x;
    const int lane = tid & 63;
    const int wv   = tid >> 6;
    const int z    = blockIdx.z;
    const int inp  = z / 3;
    const int m0   = blockIdx.y * 128;
    const int n0   = blockIdx.x * 128;

    const char* Ab = (const char*)(Rall + ((size_t)z << 20));
    const char* Bb = (const char*)(Wt4 + ((size_t)inp << 20));

    const int wm   = (wv & 1) * 64;
    const int wn   = (wv >> 1) * 64;
    const int mi   = lane & 15;
    const int quad = lane >> 4;

    f32x4 acc[4][4];
    #pragma unroll
    for (int i = 0; i < 4; ++i)
        #pragma unroll
        for (int j = 0; j < 4; ++j)
            acc[i][j] = (f32x4){0.f, 0.f, 0.f, 0.f};

    const int ra0 = tid >> 2, cb = (tid & 3) * 16;
    char* AsB = (char*)As;
    char* BsB = (char*)Bs;

    for (int k0 = 0; k0 < 1024; k0 += 32) {
        const size_t kb = (size_t)k0 * 2;
        gload_lds16(Ab + ((size_t)(m0 + ra0)      << 11) + kb + cb, AsB + wv * 1024);
        gload_lds16(Ab + ((size_t)(m0 + 64 + ra0) << 11) + kb + cb, AsB + 4096 + wv * 1024);
        gload_lds16(Bb + ((size_t)(n0 + ra0)      << 11) + kb + cb, BsB + wv * 1024);
        gload_lds16(Bb + ((size_t)(n0 + 64 + ra0) << 11) + kb + cb, BsB + 4096 + wv * 1024);
        __syncthreads();

        bf16x8 af[4], bfr[4];
        #pragma unroll
        for (int i = 0; i < 4; ++i)
            af[i] = *reinterpret_cast<const bf16x8*>(&As[(wm + i * 16 + mi) * 32 + quad * 8]);
        #pragma unroll
        for (int j = 0; j < 4; ++j)
            bfr[j] = *reinterpret_cast<const bf16x8*>(&Bs[(wn + j * 16 + mi) * 32 + quad * 8]);

        #pragma unroll
        for (int i = 0; i < 4; ++i)
            #pragma unroll
            for (int j = 0; j < 4; ++j)
                acc[i][j] = __builtin_amdgcn_mfma_f32_16x16x32_bf16(af[i], bfr[j], acc[i][j], 0, 0, 0);

        __syncthreads();
    }

    u16* Cs = Rall + ((size_t)z << 20);
    #pragma unroll
    for (int j = 0; j < 4; ++j) {
        const int col = n0 + wn + j * 16 + mi;
        #pragma unroll
        for (int i = 0; i < 4; ++i) {
            const int row = m0 + wm + i * 16 + quad * 4;
            #pragma unroll
            for (int r = 0; r < 4; ++r)
                Cs[(size_t)(row + r) * 1024 + col] = f2bf(acc[i][j][r]);
        }
    }
}

// ------------- combine sections + biases -> qb/kb bf16 [bh*256+t][64], vt bf16 [bh][80][256] -------------
__global__ __launch_bounds__(256) void combine_kernel(
    const u16* __restrict__ Y,
    const float* __restrict__ wcq, const float* __restrict__ wck, const float* __restrict__ wcv,
    const float* __restrict__ bcq, const float* __restrict__ bck, const float* __restrict__ bcv,
    const float* __restrict__ bq,  const float* __restrict__ bk,  const float* __restrict__ bv,
    u16* __restrict__ qb, u16* __restrict__ kb, u16* __restrict__ vt)
{
    int gid = blockIdx.x * 256 + threadIdx.x;       // over 3 * 2^20
    int c = gid & 1023, t = (gid >> 10) & 255, b = (gid >> 18) & 3, inp = gid >> 20;
    const float* wc = (inp == 0) ? wcq : (inp == 1) ? wck : wcv;
    const float* bconv = (inp == 0) ? bcq : (inp == 1) ? bck : bcv;
    const float* bl = (inp == 0) ? bq : (inp == 1) ? bk : bv;
    const float nrm = (inp == 2) ? 1.0f : 0.35355339059327373f;

    float w0 = wc[c], w1 = wc[1024 + c], w2 = wc[2048 + c];
    float sumw = w0 + w1 + w2, w12 = w1 + w2;

    u32 lo = gid & 0xFFFFFu;
    size_t z0 = (size_t)(inp * 3) << 20;
    float Y0  = bf2f(Y[z0 + lo]);
    float Y1  = bf2f(Y[z0 + (1u << 20) + lo]);
    float Y2  = bf2f(Y[z0 + (2u << 20) + lo]);
    float Y1p = (t > 0) ? bf2f(Y[z0 + (1u << 20) + lo - 1024]) : 0.f;
    float Y2p = (t > 0) ? bf2f(Y[z0 + (2u << 20) + lo - 1024]) : 0.f;

    float data = sumw * Y0 + w12 * (Y1 - Y1p) + w2 * (Y2 - Y2p);

    float cnt = (t == 0) ? 1.f : 8.f;
    float n0  = (t == 0) ? 0.f : ((t == 1) ? 7.f : 8.f);
    float n1  = (t == 0) ? 0.f : 8.f;
    float n2  = (t == 0) ? 1.f : 8.f;
    float val = 0.125f * (cnt * bconv[c] + nrm * (bl[c] * (n0 * w0 + n1 * w1 + n2 * w2) + data));

    int h = c >> 6, d = c & 63;
    int bh = b * 16 + h;
    u16 bfv = f2bf(val);
    if (inp == 0)
        qb[(((size_t)bh * 256 + t) << 6) + d] = bfv;
    else if (inp == 1)
        kb[(((size_t)bh * 256 + t) << 6) + d] = bfv;
    else
        vt[(size_t)bh * 80 * 256 + (size_t)d * 256 + t] = bfv;   // transposed [d][key]
}

// ------------- pad V^T rows 64..79: row 64 = 1.0 (softmax-l trick), rows 65..79 = 0 -------------
__global__ __launch_bounds__(256) void vpad_kernel(u16* __restrict__ vt)
{
    const int bh = blockIdx.x;
    const int tid = threadIdx.x;
    const int rr = tid >> 4;            // 0..15 (row 64+rr)
    const int c0 = (tid & 15) * 16;     // 16 u16 per thread
    u32 fill = (rr == 0) ? 0x3F803F80u : 0u;
    uint4 val = make_uint4(fill, fill, fill, fill);
    uint4* p = (uint4*)(vt + (size_t)bh * 80 * 256 + (size_t)(64 + rr) * 256 + c0);
    p[0] = val;
    p[1] = val;
}

// ---------------- MFMA causal attention ----------------
// One block per (b,h), 4 waves; wave w owns q-rows [64w,64w+64), loops key-tiles 0..w.
// No __syncthreads: LDS P-buffer is wave-private. Max-free softmax; l via ones-row of V^T.
__global__ __launch_bounds__(256) void attn_mfma(
    const u16* __restrict__ qb, const u16* __restrict__ kb,
    const u16* __restrict__ vt, float* __restrict__ ao)
{
    __shared__ __align__(16) u16 Ps[4][64 * 72];    // stride 72 u16: 2-way banks only
    const int bh   = blockIdx.x;
    const int tid  = threadIdx.x;
    const int wv   = tid >> 6;
    const int lane = tid & 63;
    const int mi   = lane & 15;
    const int quad = lane >> 4;

    const u16* Qb = qb + (((size_t)bh * 256 + wv * 64) << 6);
    const u16* Kb = kb + ((size_t)bh << 14);        // *256*64
    const u16* Vt = vt + (size_t)bh * 80 * 256;
    u16* P = Ps[wv];

    // Q fragments (persist across key tiles): A[m=mi][k=quad*8+j]
    bf16x8 qf[4][2];
    #pragma unroll
    for (int it = 0; it < 4; ++it)
        #pragma unroll
        for (int kc = 0; kc < 2; ++kc)
            qf[it][kc] = *(const bf16x8*)(Qb + ((it * 16 + mi) << 6) + kc * 32 + quad * 8);

    f32x4 o[4][5];
    #pragma unroll
    for (int it = 0; it < 4; ++it)
        #pragma unroll
        for (int jn = 0; jn < 5; ++jn)
            o[it][jn] = (f32x4){0.f, 0.f, 0.f, 0.f};

    for (int kt = 0; kt <= wv; ++kt) {
        // ---- S = Q @ K^T over this 64-key tile ----
        bf16x8 kf[4][2];
        #pragma unroll
        for (int jt = 0; jt < 4; ++jt)
            #pragma unroll
            for (int kc = 0; kc < 2; ++kc)
                kf[jt][kc] = *(const bf16x8*)(Kb + ((kt * 64 + jt * 16 + mi) << 6) + kc * 32 + quad * 8);

        f32x4 s[4][4];
        #pragma unroll
        for (int it = 0; it < 4; ++it)
            #pragma unroll
            for (int jt = 0; jt < 4; ++jt)
                s[it][jt] = (f32x4){0.f, 0.f, 0.f, 0.f};
        #pragma unroll
        for (int kc = 0; kc < 2; ++kc)
            #pragma unroll
            for (int it = 0; it < 4; ++it)
                #pragma unroll
                for (int jt = 0; jt < 4; ++jt)
                    s[it][jt] = __builtin_amdgcn_mfma_f32_16x16x32_bf16(qf[it][kc], kf[jt][kc], s[it][jt], 0, 0, 0);

        // ---- mask (diagonal tile only) + exp -> P (bf16, LDS, [row][key] stride 72) ----
        const bool diag = (kt == wv);
        #pragma unroll
        for (int it = 0; it < 4; ++it)
            #pragma unroll
            for (int jt = 0; jt < 4; ++jt)
                #pragma unroll
                for (int r = 0; r < 4; ++r) {
                    int qrow = it * 16 + quad * 4 + r;
                    int kcol = jt * 16 + mi;
                    float e = __expf(s[it][jt][r]);
                    if (diag && kcol > qrow) e = 0.f;
                    P[qrow * 72 + kcol] = f2bf(e);
                }

        // ---- PV: o += P @ [V | 1]^T  (A-frags from LDS, B-frags from V^T global) ----
        bf16x8 pf[4][2];
        #pragma unroll
        for (int it = 0; it < 4; ++it)
            #pragma unroll
            for (int kc = 0; kc < 2; ++kc)
                pf[it][kc] = *(const bf16x8*)(P + (it * 16 + mi) * 72 + kc * 32 + quad * 8);

        bf16x8 vf[5][2];
        #pragma unroll
        for (int jn = 0; jn < 5; ++jn)
            #pragma unroll
            for (int kc = 0; kc < 2; ++kc)
                vf[jn][kc] = *(const bf16x8*)(Vt + (size_t)(jn * 16 + mi) * 256 + kt * 64 + kc * 32 + quad * 8);

        #pragma unroll
        for (int kc = 0; kc < 2; ++kc)
            #pragma unroll
            for (int it = 0; it < 4; ++it)
                #pragma unroll
                for (int jn = 0; jn < 5; ++jn)
                    o[it][jn] = __builtin_amdgcn_mfma_f32_16x16x32_bf16(pf[it][kc], vf[jn][kc], o[it][jn], 0, 0, 0);
    }

    // ---- epilogue: l sits in n-tile 4 (ones row of V^T), lanes mi==0; broadcast & divide ----
    #pragma unroll
    for (int it = 0; it < 4; ++it) {
        float inv[4];
        #pragma unroll
        for (int r = 0; r < 4; ++r) {
            float lv = __shfl(o[it][4][r], (lane & 48));   // from lane quad*16+0
            inv[r] = 1.0f / lv;
        }
        #pragma unroll
        for (int jn = 0; jn < 4; ++jn)
            #pragma unroll
            for (int r = 0; r < 4; ++r) {
                int row = wv * 64 + it * 16 + quad * 4 + r;
                ao[(((size_t)bh * 256 + row) << 6) + jn * 16 + mi] = o[it][jn][r] * inv[r];
            }
    }
}

// ---------------- up-dense (64x64) + head-merge into [B, n, D] (bf16 out) ----------------
__global__ __launch_bounds__(256) void updense_kernel(
    const float* __restrict__ ao, const float* __restrict__ Wup,
    const float* __restrict__ bup, u16* __restrict__ ms)
{
    __shared__ float Ws[64 * 64];
    __shared__ float rows[4 * 64];
    const int tid = threadIdx.x;

    #pragma unroll
    for (int i = 0; i < 4; ++i)
        ((float4*)Ws)[tid + 256 * i] = ((const float4*)Wup)[tid + 256 * i];
    rows[tid] = ao[(size_t)blockIdx.x * 256 + tid];
    __syncthreads();

    const int r = tid >> 6, dp = tid & 63;
    const int R = blockIdx.x * 4 + r;
    const int b = R >> 12;
    const int h = (R >> 8) & 15;
    const int m = R & 255;

    float acc = bup[dp];
    #pragma unroll
    for (int d = 0; d < 64; ++d)
        acc += rows[r * 64 + d] * Ws[d * 64 + dp];

    ms[((size_t)(b * Nc + m) << 10) + h * 64 + dp] = f2bf(acc);
}

// ------------- final dense (ms @ Wc^T + bc), broadcast each row 8x into d_out -------------
__global__ __launch_bounds__(256) void gemm_final(
    const u16* __restrict__ A, const u16* __restrict__ Bt,
    const float* __restrict__ bias, float* __restrict__ out)
{
    __shared__ __align__(16) u16 As[128 * 32];
    __shared__ __align__(16) u16 Bs[128 * 32];

    const int tid  = threadIdx.x;
    const int lane = tid & 63;
    const int wv   = tid >> 6;
    const int m0   = blockIdx.y * 128;
    const int n0   = blockIdx.x * 128;

    const int wm   = (wv & 1) * 64;
    const int wn   = (wv >> 1) * 64;
    const int mi   = lane & 15;
    const int quad = lane >> 4;

    f32x4 acc[4][4];
    #pragma unroll
    for (int i = 0; i < 4; ++i)
        #pragma unroll
        for (int j = 0; j < 4; ++j)
            acc[i][j] = (f32x4){0.f, 0.f, 0.f, 0.f};

    const char* Ab = (const char*)A;
    const char* Bb = (const char*)Bt;
    const int ra0 = tid >> 2, cb = (tid & 3) * 16;
    char* AsB = (char*)As;
    char* BsB = (char*)Bs;

    for (int k0 = 0; k0 < 1024; k0 += 32) {
        const size_t kb = (size_t)k0 * 2;
        gload_lds16(Ab + ((size_t)(m0 + ra0)      << 11) + kb + cb, AsB + wv * 1024);
        gload_lds16(Ab + ((size_t)(m0 + 64 + ra0) << 11) + kb + cb, AsB + 4096 + wv * 1024);
        gload_lds16(Bb + ((size_t)(n0 + ra0)      << 11) + kb + cb, BsB + wv * 1024);
        gload_lds16(Bb + ((size_t)(n0 + 64 + ra0) << 11) + kb + cb, BsB + 4096 + wv * 1024);
        __syncthreads();

        bf16x8 af[4], bfr[4];
        #pragma unroll
        for (int i = 0; i < 4; ++i)
            af[i] = *reinterpret_cast<const bf16x8*>(&As[(wm + i * 16 + mi) * 32 + quad * 8]);
        #pragma unroll
        for (int j = 0; j < 4; ++j)
            bfr[j] = *reinterpret_cast<const bf16x8*>(&Bs[(wn + j * 16 + mi) * 32 + quad * 8]);

        #pragma unroll
        for (int i = 0; i < 4; ++i)
            #pragma unroll
            for (int j = 0; j < 4; ++j)
                acc[i][j] = __builtin_amdgcn_mfma_f32_16x16x32_bf16(af[i], bfr[j], acc[i][j], 0, 0, 0);

        __syncthreads();
    }

    #pragma unroll
    for (int j = 0; j < 4; ++j) {
        const int col = n0 + wn + j * 16 + mi;
        const float bv = bias[col];
        #pragma unroll
        for (int i = 0; i < 4; ++i) {
            const int row = m0 + wm + i * 16 + quad * 4;
            #pragma unroll
            for (int r = 0; r < 4; ++r) {
                const int rr = row + r;
                const int b = rr >> 8, t = rr & 255;
                float val = acc[i][j][r] + bv;
                float* po = out + (((size_t)b * Sc + (t << 3)) << 10) + col;
                #pragma unroll
                for (int rep = 0; rep < 8; ++rep)
                    po[(size_t)rep << 10] = val;
            }
        }
    }
}

extern "C" void kernel_launch(void* const* d_in, const int* in_sizes, int n_in,
                              void* d_out, int out_size, void* d_ws, size_t ws_size,
                              hipStream_t stream) {
    const float* q   = (const float*)d_in[0];
    const float* k   = (const float*)d_in[1];
    const float* v   = (const float*)d_in[2];
    const float* Wq  = (const float*)d_in[3];
    const float* bq  = (const float*)d_in[4];
    const float* Wk  = (const float*)d_in[5];
    const float* bk  = (const float*)d_in[6];
    const float* Wv  = (const float*)d_in[7];
    const float* bv  = (const float*)d_in[8];
    const float* Wup = (const float*)d_in[9];
    const float* bup = (const float*)d_in[10];
    const float* Wc  = (const float*)d_in[11];
    const float* bc  = (const float*)d_in[12];
    const float* wcq = (const float*)d_in[13];
    const float* bcq = (const float*)d_in[14];
    const float* wck = (const float*)d_in[15];
    const float* bck = (const float*)d_in[16];
    const float* wcv = (const float*)d_in[17];
    const float* bcv = (const float*)d_in[18];

    // Rall/Y (18.9 MB bf16) lives in d_out; gemm_final rewrites all of d_out at the end.
    u16* Rall = (u16*)d_out;

    char* wsb = (char*)d_ws;
    // ws layout (bytes), total 20.5 MB:
    //   0        : Wt4 bf16 [4][1024][1024]   8,388,608
    //   8388608  : qb  bf16 [64*256][64]      2,097,152
    //   10485760 : kb  bf16 [64*256][64]      2,097,152
    //   12582912 : vt  bf16 [64][80][256]     2,621,440
    //   15204352 : ao  fp32 [64*256][64]      4,194,304
    //   19398656 : ms  bf16 [1024][1024]      2,097,152
    u16*   Wt4 = (u16*)wsb;
    u16*   qb  = (u16*)(wsb + 8388608);
    u16*   kb  = (u16*)(wsb + 10485760);
    u16*   vt  = (u16*)(wsb + 12582912);
    float* ao  = (float*)(wsb + 15204352);
    u16*   ms  = (u16*)(wsb + 19398656);

    // 1. cast+transpose all 4 weights
    cast_wt4_kernel<<<dim3(16, 16, 4), 256, 0, stream>>>(Wq, Wk, Wv, Wc, Wt4);
    // 2. stage 3 bf16 sections per input (disjoint 8-row windows, unconditional loads)
    stage_kernel<<<3072, 256, 0, stream>>>(q, k, v, Rall);
    // 3. section GEMMs, in-place bf16
    gemm_sec<<<dim3(8, 8, 9), 256, 0, stream>>>(Rall, Wt4);
    // 4. combine sections + biases -> qb/kb (row-major) + vt (transposed)
    combine_kernel<<<12288, 256, 0, stream>>>(Rall, wcq, wck, wcv, bcq, bck, bcv,
                                              bq, bk, bv, qb, kb, vt);
    // 4b. V^T ones/zero pad rows (softmax-l trick)
    vpad_kernel<<<64, 256, 0, stream>>>(vt);
    // 5. MFMA causal attention
    attn_mfma<<<64, 256, 0, stream>>>(qb, kb, vt, ao);
    // 6. up-dense + merge heads -> ms bf16 [B*n][D]
    updense_kernel<<<(Bc * Hc * Nc) / 4, 256, 0, stream>>>(ao, Wup, bup, ms);
    // 7. final dense + 8x broadcast write into d_out
    gemm_final<<<dim3(8, 8), 256, 0, stream>>>(ms, Wt4 + ((size_t)3 << 20), bc, (float*)d_out);
}

// Round 2
// 276.373 us; speedup vs baseline: 1.0418x; 1.0279x over previous
//
#include <hip/hip_runtime.h>
#include <cstdint>
#include <cstddef>

// Problem constants
#define Bc  4
#define Sc  2048
#define Dc  1024
#define Hc  16
#define DDc 64
#define Nc  256   // pooled length

typedef unsigned short u16;
typedef unsigned int   u32;
typedef __bf16 bf16_t;
typedef bf16_t bf16x8 __attribute__((ext_vector_type(8)));
typedef float  f32x4  __attribute__((ext_vector_type(4)));

__device__ __forceinline__ u16 f2bf(float x) {
    u32 u = __float_as_uint(x);
    return (u16)((u + 0x7FFFu + ((u >> 16) & 1u)) >> 16);   // RNE
}
__device__ __forceinline__ u32 pack2(float a, float b) {
    return (u32)f2bf(a) | ((u32)f2bf(b) << 16);
}
__device__ __forceinline__ uint2 pack4(float4 x) {
    return make_uint2(pack2(x.x, x.y), pack2(x.z, x.w));
}
__device__ __forceinline__ float bf2f(u16 x) {
    return __uint_as_float((u32)x << 16);
}
__device__ __forceinline__ float4 f4add(float4 a, float4 b) {
    return make_float4(a.x + b.x, a.y + b.y, a.z + b.z, a.w + b.w);
}

// async global->LDS, 16B per lane
__device__ __forceinline__ void gload_lds16(const void* gp, void* lp) {
    __builtin_amdgcn_global_load_lds(
        reinterpret_cast<const __attribute__((address_space(1))) void*>(
            reinterpret_cast<uintptr_t>(gp)),
        reinterpret_cast<__attribute__((address_space(3))) void*>(
            reinterpret_cast<uintptr_t>(lp)),
        16, 0, 0);
}

// ------------- cast + transpose 4 weights: W[K][N] fp32 -> Wt[N][K] bf16 -------------
__global__ __launch_bounds__(256) void cast_wt4_kernel(
    const float* __restrict__ Wq, const float* __restrict__ Wk,
    const float* __restrict__ Wv, const float* __restrict__ Wc,
    u16* __restrict__ Wt4)
{
    __shared__ float T[64][65];
    const int z = blockIdx.z;
    const float* W = (z == 0) ? Wq : (z == 1) ? Wk : (z == 2) ? Wv : Wc;
    u16* Wt = Wt4 + ((size_t)z << 20);
    const int k0 = blockIdx.y * 64, n0 = blockIdx.x * 64;
    const int c = threadIdx.x & 63, r4 = threadIdx.x >> 6;
    #pragma unroll
    for (int i = 0; i < 16; ++i) {
        int r = i * 4 + r4;
        T[r][c] = W[(size_t)(k0 + r) * 1024 + n0 + c];
    }
    __syncthreads();
    #pragma unroll
    for (int i = 0; i < 16; ++i) {
        int r = i * 4 + r4;
        Wt[(size_t)(n0 + r) * 1024 + k0 + c] = f2bf(T[c][r]);
    }
}

// ------------- staging: 3 bf16 sections per input into Rall -------------
// Each thread owns the DISJOINT 8-row window [8t-1, 8t+6] (one float4 column slice):
//   sec1[t] = x[8t-1] (first row; 0 for t==0)
//   sec2[t] = x[8t]   (second row)
//   sec0[t+1] = sum of the 8 rows  (sec0[t] = sum x[8t-9..8t-2])
//   sec0[0] = 0 (written by thread t==0)
__global__ __launch_bounds__(256) void stage_kernel(
    const float* __restrict__ q, const float* __restrict__ k,
    const float* __restrict__ v, u16* __restrict__ R)
{
    int gid = blockIdx.x * 256 + threadIdx.x;       // over 3 * 2^18 float4-groups
    int c4 = gid & 255, t = (gid >> 8) & 255, b = (gid >> 16) & 3, inp = gid >> 18;
    const float* src = (inp == 0) ? q : (inp == 1) ? k : v;
    const float4* Xb = (const float4*)(src + (size_t)b * Sc * Dc) + c4;
    const float4* Xr = Xb + ((ptrdiff_t)(t << 3) - 1) * 256;   // row 8t-1

    float4 r[8];
    if (t > 0) {
        #pragma unroll
        for (int i = 0; i < 8; ++i) r[i] = Xr[(ptrdiff_t)i * 256];
    } else {
        r[0] = make_float4(0.f, 0.f, 0.f, 0.f);
        #pragma unroll
        for (int i = 1; i < 8; ++i) r[i] = Xr[(ptrdiff_t)i * 256];
    }

    float4 s8 = f4add(f4add(f4add(r[0], r[1]), f4add(r[2], r[3])),
                      f4add(f4add(r[4], r[5]), f4add(r[6], r[7])));

    size_t s0 = ((size_t)(inp * 3) << 20) + (((u32)(b * 256 + t)) << 10) + c4 * 4;
    *(uint2*)(R + s0 + (1u << 20)) = pack4(r[0]);        // sec1[t] = x[8t-1]
    *(uint2*)(R + s0 + (2u << 20)) = pack4(r[1]);        // sec2[t] = x[8t]
    if (t < 255) *(uint2*)(R + s0 + 1024) = pack4(s8);   // sec0[t+1]
    if (t == 0)  *(uint2*)(R + s0) = make_uint2(0u, 0u); // sec0[0] = 0
}

// ------------- section GEMM, in-place: Y_z = A_z @ Wt_inp^T (bf16 out over A_z) -------------
__global__ __launch_bounds__(256) void gemm_sec(
    u16* __restrict__ Rall, const u16* __restrict__ Wt4)
{
    __shared__ __align__(16) u16 As[128 * 32];
    __shared__ __align__(16) u16 Bs[128 * 32];

    const int tid  = threadIdx.x;
    const int lane = tid & 63;
    const int wv   = tid >> 6;
    const int z    = blockIdx.z;
    const int inp  = z / 3;
    const int m0   = blockIdx.y * 128;
    const int n0   = blockIdx.x * 128;

    const char* Ab = (const char*)(Rall + ((size_t)z << 20));
    const char* Bb = (const char*)(Wt4 + ((size_t)inp << 20));

    const int wm   = (wv & 1) * 64;
    const int wn   = (wv >> 1) * 64;
    const int mi   = lane & 15;
    const int quad = lane >> 4;

    f32x4 acc[4][4];
    #pragma unroll
    for (int i = 0; i < 4; ++i)
        #pragma unroll
        for (int j = 0; j < 4; ++j)
            acc[i][j] = (f32x4){0.f, 0.f, 0.f, 0.f};

    const int ra0 = tid >> 2, cb = (tid & 3) * 16;
    char* AsB = (char*)As;
    char* BsB = (char*)Bs;

    for (int k0 = 0; k0 < 1024; k0 += 32) {
        const size_t kb = (size_t)k0 * 2;
        gload_lds16(Ab + ((size_t)(m0 + ra0)      << 11) + kb + cb, AsB + wv * 1024);
        gload_lds16(Ab + ((size_t)(m0 + 64 + ra0) << 11) + kb + cb, AsB + 4096 + wv * 1024);
        gload_lds16(Bb + ((size_t)(n0 + ra0)      << 11) + kb + cb, BsB + wv * 1024);
        gload_lds16(Bb + ((size_t)(n0 + 64 + ra0) << 11) + kb + cb, BsB + 4096 + wv * 1024);
        __syncthreads();

        bf16x8 af[4], bfr[4];
        #pragma unroll
        for (int i = 0; i < 4; ++i)
            af[i] = *reinterpret_cast<const bf16x8*>(&As[(wm + i * 16 + mi) * 32 + quad * 8]);
        #pragma unroll
        for (int j = 0; j < 4; ++j)
            bfr[j] = *reinterpret_cast<const bf16x8*>(&Bs[(wn + j * 16 + mi) * 32 + quad * 8]);

        #pragma unroll
        for (int i = 0; i < 4; ++i)
            #pragma unroll
            for (int j = 0; j < 4; ++j)
                acc[i][j] = __builtin_amdgcn_mfma_f32_16x16x32_bf16(af[i], bfr[j], acc[i][j], 0, 0, 0);

        __syncthreads();
    }

    u16* Cs = Rall + ((size_t)z << 20);
    #pragma unroll
    for (int j = 0; j < 4; ++j) {
        const int col = n0 + wn + j * 16 + mi;
        #pragma unroll
        for (int i = 0; i < 4; ++i) {
            const int row = m0 + wm + i * 16 + quad * 4;
            #pragma unroll
            for (int r = 0; r < 4; ++r)
                Cs[(size_t)(row + r) * 1024 + col] = f2bf(acc[i][j][r]);
        }
    }
}

// ------------- combine sections + biases -> qb/kb bf16 [bh*256+t][64], vt bf16 [bh][80][256] -------------
__global__ __launch_bounds__(256) void combine_kernel(
    const u16* __restrict__ Y,
    const float* __restrict__ wcq, const float* __restrict__ wck, const float* __restrict__ wcv,
    const float* __restrict__ bcq, const float* __restrict__ bck, const float* __restrict__ bcv,
    const float* __restrict__ bq,  const float* __restrict__ bk,  const float* __restrict__ bv,
    u16* __restrict__ qb, u16* __restrict__ kb, u16* __restrict__ vt)
{
    int gid = blockIdx.x * 256 + threadIdx.x;       // over 3 * 2^20
    int c = gid & 1023, t = (gid >> 10) & 255, b = (gid >> 18) & 3, inp = gid >> 20;
    const float* wc = (inp == 0) ? wcq : (inp == 1) ? wck : wcv;
    const float* bconv = (inp == 0) ? bcq : (inp == 1) ? bck : bcv;
    const float* bl = (inp == 0) ? bq : (inp == 1) ? bk : bv;
    const float nrm = (inp == 2) ? 1.0f : 0.35355339059327373f;

    float w0 = wc[c], w1 = wc[1024 + c], w2 = wc[2048 + c];
    float sumw = w0 + w1 + w2, w12 = w1 + w2;

    u32 lo = gid & 0xFFFFFu;
    size_t z0 = (size_t)(inp * 3) << 20;
    float Y0  = bf2f(Y[z0 + lo]);
    float Y1  = bf2f(Y[z0 + (1u << 20) + lo]);
    float Y2  = bf2f(Y[z0 + (2u << 20) + lo]);
    float Y1p = (t > 0) ? bf2f(Y[z0 + (1u << 20) + lo - 1024]) : 0.f;
    float Y2p = (t > 0) ? bf2f(Y[z0 + (2u << 20) + lo - 1024]) : 0.f;

    float data = sumw * Y0 + w12 * (Y1 - Y1p) + w2 * (Y2 - Y2p);

    float cnt = (t == 0) ? 1.f : 8.f;
    float n0  = (t == 0) ? 0.f : ((t == 1) ? 7.f : 8.f);
    float n1  = (t == 0) ? 0.f : 8.f;
    float n2  = (t == 0) ? 1.f : 8.f;
    float val = 0.125f * (cnt * bconv[c] + nrm * (bl[c] * (n0 * w0 + n1 * w1 + n2 * w2) + data));

    int h = c >> 6, d = c & 63;
    int bh = b * 16 + h;
    u16 bfv = f2bf(val);
    if (inp == 0)
        qb[(((size_t)bh * 256 + t) << 6) + d] = bfv;
    else if (inp == 1)
        kb[(((size_t)bh * 256 + t) << 6) + d] = bfv;
    else
        vt[(size_t)bh * 80 * 256 + (size_t)d * 256 + t] = bfv;   // transposed [d][key]
}

// ------------- pad V^T rows 64..79: row 64 = 1.0 (softmax-l trick), rows 65..79 = 0 -------------
__global__ __launch_bounds__(256) void vpad_kernel(u16* __restrict__ vt)
{
    const int bh = blockIdx.x;
    const int tid = threadIdx.x;
    const int rr = tid >> 4;            // 0..15 (row 64+rr)
    const int c0 = (tid & 15) * 16;     // 16 u16 per thread
    u32 fill = (rr == 0) ? 0x3F803F80u : 0u;
    uint4 val = make_uint4(fill, fill, fill, fill);
    uint4* p = (uint4*)(vt + (size_t)bh * 80 * 256 + (size_t)(64 + rr) * 256 + c0);
    p[0] = val;
    p[1] = val;
}

// ---------------- MFMA causal attention ----------------
// One block per (b,h), 4 waves; wave w owns q-rows [64w,64w+64), loops key-tiles 0..w.
// No __syncthreads: LDS P-buffer is wave-private. Max-free softmax; l via ones-row of V^T.
__global__ __launch_bounds__(256) void attn_mfma(
    const u16* __restrict__ qb, const u16* __restrict__ kb,
    const u16* __restrict__ vt, float* __restrict__ ao)
{
    __shared__ __align__(16) u16 Ps[4][64 * 72];    // stride 72 u16: 2-way banks only
    const int bh   = blockIdx.x;
    const int tid  = threadIdx.x;
    const int wv   = tid >> 6;
    const int lane = tid & 63;
    const int mi   = lane & 15;
    const int quad = lane >> 4;

    const u16* Qb = qb + (((size_t)bh * 256 + wv * 64) << 6);
    const u16* Kb = kb + ((size_t)bh << 14);        // *256*64
    const u16* Vt = vt + (size_t)bh * 80 * 256;
    u16* P = Ps[wv];

    // Q fragments (persist across key tiles): A[m=mi][k=quad*8+j]
    bf16x8 qf[4][2];
    #pragma unroll
    for (int it = 0; it < 4; ++it)
        #pragma unroll
        for (int kc = 0; kc < 2; ++kc)
            qf[it][kc] = *(const bf16x8*)(Qb + ((it * 16 + mi) << 6) + kc * 32 + quad * 8);

    f32x4 o[4][5];
    #pragma unroll
    for (int it = 0; it < 4; ++it)
        #pragma unroll
        for (int jn = 0; jn < 5; ++jn)
            o[it][jn] = (f32x4){0.f, 0.f, 0.f, 0.f};

    for (int kt = 0; kt <= wv; ++kt) {
        // ---- S = Q @ K^T over this 64-key tile ----
        bf16x8 kf[4][2];
        #pragma unroll
        for (int jt = 0; jt < 4; ++jt)
            #pragma unroll
            for (int kc = 0; kc < 2; ++kc)
                kf[jt][kc] = *(const bf16x8*)(Kb + ((kt * 64 + jt * 16 + mi) << 6) + kc * 32 + quad * 8);

        f32x4 s[4][4];
        #pragma unroll
        for (int it = 0; it < 4; ++it)
            #pragma unroll
            for (int jt = 0; jt < 4; ++jt)
                s[it][jt] = (f32x4){0.f, 0.f, 0.f, 0.f};
        #pragma unroll
        for (int kc = 0; kc < 2; ++kc)
            #pragma unroll
            for (int it = 0; it < 4; ++it)
                #pragma unroll
                for (int jt = 0; jt < 4; ++jt)
                    s[it][jt] = __builtin_amdgcn_mfma_f32_16x16x32_bf16(qf[it][kc], kf[jt][kc], s[it][jt], 0, 0, 0);

        // ---- mask (diagonal tile only) + exp -> P (bf16, LDS, [row][key] stride 72) ----
        const bool diag = (kt == wv);
        #pragma unroll
        for (int it = 0; it < 4; ++it)
            #pragma unroll
            for (int jt = 0; jt < 4; ++jt)
                #pragma unroll
                for (int r = 0; r < 4; ++r) {
                    int qrow = it * 16 + quad * 4 + r;
                    int kcol = jt * 16 + mi;
                    float e = __expf(s[it][jt][r]);
                    if (diag && kcol > qrow) e = 0.f;
                    P[qrow * 72 + kcol] = f2bf(e);
                }

        // ---- PV: o += P @ [V | 1]^T  (A-frags from LDS, B-frags from V^T global) ----
        bf16x8 pf[4][2];
        #pragma unroll
        for (int it = 0; it < 4; ++it)
            #pragma unroll
            for (int kc = 0; kc < 2; ++kc)
                pf[it][kc] = *(const bf16x8*)(P + (it * 16 + mi) * 72 + kc * 32 + quad * 8);

        bf16x8 vf[5][2];
        #pragma unroll
        for (int jn = 0; jn < 5; ++jn)
            #pragma unroll
            for (int kc = 0; kc < 2; ++kc)
                vf[jn][kc] = *(const bf16x8*)(Vt + (size_t)(jn * 16 + mi) * 256 + kt * 64 + kc * 32 + quad * 8);

        #pragma unroll
        for (int kc = 0; kc < 2; ++kc)
            #pragma unroll
            for (int it = 0; it < 4; ++it)
                #pragma unroll
                for (int jn = 0; jn < 5; ++jn)
                    o[it][jn] = __builtin_amdgcn_mfma_f32_16x16x32_bf16(pf[it][kc], vf[jn][kc], o[it][jn], 0, 0, 0);
    }

    // ---- epilogue: l sits in n-tile 4 (ones row of V^T), lanes mi==0; broadcast & divide ----
    #pragma unroll
    for (int it = 0; it < 4; ++it) {
        float inv[4];
        #pragma unroll
        for (int r = 0; r < 4; ++r) {
            float lv = __shfl(o[it][4][r], (lane & 48));   // from lane quad*16+0
            inv[r] = 1.0f / lv;
        }
        #pragma unroll
        for (int jn = 0; jn < 4; ++jn)
            #pragma unroll
            for (int r = 0; r < 4; ++r) {
                int row = wv * 64 + it * 16 + quad * 4 + r;
                ao[(((size_t)bh * 256 + row) << 6) + jn * 16 + mi] = o[it][jn][r] * inv[r];
            }
    }
}

// ---------------- up-dense (64x64) + head-merge into [B, n, D] (bf16 out) ----------------
__global__ __launch_bounds__(256) void updense_kernel(
    const float* __restrict__ ao, const float* __restrict__ Wup,
    const float* __restrict__ bup, u16* __restrict__ ms)
{
    __shared__ float Ws[64 * 64];
    __shared__ float rows[4 * 64];
    const int tid = threadIdx.x;

    #pragma unroll
    for (int i = 0; i < 4; ++i)
        ((float4*)Ws)[tid + 256 * i] = ((const float4*)Wup)[tid + 256 * i];
    rows[tid] = ao[(size_t)blockIdx.x * 256 + tid];
    __syncthreads();

    const int r = tid >> 6, dp = tid & 63;
    const int R = blockIdx.x * 4 + r;
    const int b = R >> 12;
    const int h = (R >> 8) & 15;
    const int m = R & 255;

    float acc = bup[dp];
    #pragma unroll
    for (int d = 0; d < 64; ++d)
        acc += rows[r * 64 + d] * Ws[d * 64 + dp];

    ms[((size_t)(b * Nc + m) << 10) + h * 64 + dp] = f2bf(acc);
}

// ------------- final dense: C = ms @ Wc^T + bc, fp32 [1024][1024] into ws -------------
// 64x64 tiles, grid 16x16 = 256 blocks (1 per CU) -- replaces the 64-block fused
// version whose 2.4% occupancy + 8x scalar broadcast stores ran at 1.2 TB/s.
__global__ __launch_bounds__(256) void gemm_out(
    const u16* __restrict__ A, const u16* __restrict__ Bt,
    const float* __restrict__ bias, float* __restrict__ C)
{
    __shared__ __align__(16) u16 As[64 * 32];
    __shared__ __align__(16) u16 Bs[64 * 32];

    const int tid  = threadIdx.x;
    const int lane = tid & 63;
    const int wv   = tid >> 6;
    const int m0   = blockIdx.y * 64;
    const int n0   = blockIdx.x * 64;

    const int wm   = (wv >> 1) * 32;
    const int wn   = (wv & 1) * 32;
    const int mi   = lane & 15;
    const int quad = lane >> 4;

    f32x4 acc[2][2];
    #pragma unroll
    for (int i = 0; i < 2; ++i)
        #pragma unroll
        for (int j = 0; j < 2; ++j)
            acc[i][j] = (f32x4){0.f, 0.f, 0.f, 0.f};

    const char* Ab = (const char*)A;
    const char* Bb = (const char*)Bt;
    const int ra0 = tid >> 2, cb = (tid & 3) * 16;
    char* AsB = (char*)As;
    char* BsB = (char*)Bs;

    for (int k0 = 0; k0 < 1024; k0 += 32) {
        const size_t kb = (size_t)k0 * 2;
        gload_lds16(Ab + ((size_t)(m0 + ra0) << 11) + kb + cb, AsB + wv * 1024);
        gload_lds16(Bb + ((size_t)(n0 + ra0) << 11) + kb + cb, BsB + wv * 1024);
        __syncthreads();

        bf16x8 af[2], bfr[2];
        #pragma unroll
        for (int i = 0; i < 2; ++i)
            af[i] = *reinterpret_cast<const bf16x8*>(&As[(wm + i * 16 + mi) * 32 + quad * 8]);
        #pragma unroll
        for (int j = 0; j < 2; ++j)
            bfr[j] = *reinterpret_cast<const bf16x8*>(&Bs[(wn + j * 16 + mi) * 32 + quad * 8]);

        #pragma unroll
        for (int i = 0; i < 2; ++i)
            #pragma unroll
            for (int j = 0; j < 2; ++j)
                acc[i][j] = __builtin_amdgcn_mfma_f32_16x16x32_bf16(af[i], bfr[j], acc[i][j], 0, 0, 0);

        __syncthreads();
    }

    #pragma unroll
    for (int j = 0; j < 2; ++j) {
        const int col = n0 + wn + j * 16 + mi;
        const float bv = bias[col];
        #pragma unroll
        for (int i = 0; i < 2; ++i) {
            const int row = m0 + wm + i * 16 + quad * 4;
            #pragma unroll
            for (int r = 0; r < 4; ++r)
                C[(size_t)(row + r) * 1024 + col] = acc[i][j][r] + bv;
        }
    }
}

// ------------- upsample 8x: out[b, t, :] = C[b*256 + t/8, :], coalesced float4 -------------
__global__ __launch_bounds__(256) void upsample_kernel(
    const float* __restrict__ C, float* __restrict__ out)
{
    const float4* C4  = (const float4*)C;
    float4*       out4 = (float4*)out;
    int idx0 = blockIdx.x * 1024 + threadIdx.x;
    #pragma unroll
    for (int rep = 0; rep < 4; ++rep) {
        int o4   = idx0 + rep * 256;       // over 2^21 float4s
        int col4 = o4 & 255;
        int rowo = o4 >> 8;                // 0..8191 output row
        int b    = rowo >> 11;
        int tc   = (rowo & 2047) >> 3;     // pooled row
        out4[o4] = C4[(size_t)((b << 8) + tc) * 256 + col4];
    }
}

extern "C" void kernel_launch(void* const* d_in, const int* in_sizes, int n_in,
                              void* d_out, int out_size, void* d_ws, size_t ws_size,
                              hipStream_t stream) {
    const float* q   = (const float*)d_in[0];
    const float* k   = (const float*)d_in[1];
    const float* v   = (const float*)d_in[2];
    const float* Wq  = (const float*)d_in[3];
    const float* bq  = (const float*)d_in[4];
    const float* Wk  = (const float*)d_in[5];
    const float* bk  = (const float*)d_in[6];
    const float* Wv  = (const float*)d_in[7];
    const float* bv  = (const float*)d_in[8];
    const float* Wup = (const float*)d_in[9];
    const float* bup = (const float*)d_in[10];
    const float* Wc  = (const float*)d_in[11];
    const float* bc  = (const float*)d_in[12];
    const float* wcq = (const float*)d_in[13];
    const float* bcq = (const float*)d_in[14];
    const float* wck = (const float*)d_in[15];
    const float* bck = (const float*)d_in[16];
    const float* wcv = (const float*)d_in[17];
    const float* bcv = (const float*)d_in[18];

    // Rall/Y (18.9 MB bf16) lives in d_out; upsample rewrites all of d_out at the end.
    u16* Rall = (u16*)d_out;

    char* wsb = (char*)d_ws;
    // ws layout (bytes), total 20.5 MB:
    //   0        : Wt4 bf16 [4][1024][1024]   8,388,608
    //   8388608  : qb  bf16 [64*256][64]      2,097,152
    //   10485760 : kb  bf16 [64*256][64]      2,097,152
    //   12582912 : vt  bf16 [64][80][256]     2,621,440
    //   15204352 : ao  fp32 [64*256][64]      4,194,304   (reused as C fp32 [1024][1024])
    //   19398656 : ms  bf16 [1024][1024]      2,097,152
    u16*   Wt4 = (u16*)wsb;
    u16*   qb  = (u16*)(wsb + 8388608);
    u16*   kb  = (u16*)(wsb + 10485760);
    u16*   vt  = (u16*)(wsb + 12582912);
    float* ao  = (float*)(wsb + 15204352);
    u16*   ms  = (u16*)(wsb + 19398656);
    float* Cf  = ao;   // ao is dead after updense_kernel; reuse for final-dense C

    // 1. cast+transpose all 4 weights
    cast_wt4_kernel<<<dim3(16, 16, 4), 256, 0, stream>>>(Wq, Wk, Wv, Wc, Wt4);
    // 2. stage 3 bf16 sections per input (disjoint 8-row windows, unconditional loads)
    stage_kernel<<<3072, 256, 0, stream>>>(q, k, v, Rall);
    // 3. section GEMMs, in-place bf16
    gemm_sec<<<dim3(8, 8, 9), 256, 0, stream>>>(Rall, Wt4);
    // 4. combine sections + biases -> qb/kb (row-major) + vt (transposed)
    combine_kernel<<<12288, 256, 0, stream>>>(Rall, wcq, wck, wcv, bcq, bck, bcv,
                                              bq, bk, bv, qb, kb, vt);
    // 4b. V^T ones/zero pad rows (softmax-l trick)
    vpad_kernel<<<64, 256, 0, stream>>>(vt);
    // 5. MFMA causal attention
    attn_mfma<<<64, 256, 0, stream>>>(qb, kb, vt, ao);
    // 6. up-dense + merge heads -> ms bf16 [B*n][D]
    updense_kernel<<<(Bc * Hc * Nc) / 4, 256, 0, stream>>>(ao, Wup, bup, ms);
    // 7. final dense -> C fp32 (256 blocks, 1/CU)
    gemm_out<<<dim3(16, 16), 256, 0, stream>>>(ms, Wt4 + ((size_t)3 << 20), bc, Cf);
    // 8. 8x upsample broadcast, coalesced float4 writes
    upsample_kernel<<<2048, 256, 0, stream>>>(Cf, (float*)d_out);
}